// Round 6
// baseline (97.693 us; speedup 1.0000x reference)
//
#include <hip/hip_runtime.h>
#include <hip/hip_bf16.h>

#define S_DIM 4
#define N_PTS 4096
#define P_TOT (S_DIM * N_PTS)   // 16384
#define HID 64
#define KNB 16

#define CELL_H 0.125f
#define CAP 352                  // per-wave candidate buffer (LDS)
#define PROJ_BLKS 256            // 64 points per block, 4 per wave

// ---------------- Kernel 1: fused projections + grid build ----------------
// blocks [0, PROJ_BLKS): qpe/kpe/v projections, 64 points per block,
//   register-blocked 4 points per wave.
// blocks [PROJ_BLKS, PROJ_BLKS+S_DIM): per-scene 8^3 cell grid build.
__global__ __launch_bounds__(1024) void pre_kernel(
    const float* __restrict__ x, const float* __restrict__ pos,
    const float* __restrict__ Wq, const float* __restrict__ bq,
    const float* __restrict__ Wk, const float* __restrict__ bk,
    const float* __restrict__ Wv, const float* __restrict__ bv,
    const float* __restrict__ Wpe, const float* __restrict__ bpe,
    float* __restrict__ qpe, float* __restrict__ kpe, float* __restrict__ vout,
    int* __restrict__ cell_start, float4* __restrict__ gpts)
{
    int tid = threadIdx.x;

    if (blockIdx.x < PROJ_BLKS) {
        // ---------------- projection path ----------------
        __shared__ float xs[64][64];     // 16 KB
        __shared__ float psf[192];       // 64 pts x 3
        int h = tid & 63;
        int wv = tid >> 6;               // wave 0..15
        int g0 = blockIdx.x * 64;

        ((float4*)xs)[tid] = ((const float4*)(x + (size_t)g0 * 64))[tid];
        if (tid < 48)
            ((float4*)psf)[tid] = ((const float4*)(pos + (size_t)g0 * 3))[tid];
        __syncthreads();

        int pbase = wv * 4;
        float aq[4], ak[4], av[4];
        #pragma unroll
        for (int p = 0; p < 4; ++p) { aq[p] = bq[h]; ak[p] = bk[h]; av[p] = bv[h]; }

        #pragma unroll 8
        for (int f = 0; f < 64; ++f) {
            float wq = Wq[f * 64 + h];
            float wk = Wk[f * 64 + h];
            float wvv = Wv[f * 64 + h];
            #pragma unroll
            for (int p = 0; p < 4; ++p) {
                float xf = xs[pbase + p][f];
                aq[p] = fmaf(xf, wq, aq[p]);
                ak[p] = fmaf(xf, wk, ak[p]);
                av[p] = fmaf(xf, wvv, av[p]);
            }
        }

        float wpe0 = Wpe[0 * 64 + h], wpe1 = Wpe[1 * 64 + h], wpe2 = Wpe[2 * 64 + h];
        float bpeh = bpe[h];
        #pragma unroll
        for (int p = 0; p < 4; ++p) {
            int pp = pbase + p;
            float pe = fmaf(psf[pp * 3 + 0], wpe0,
                       fmaf(psf[pp * 3 + 1], wpe1,
                       fmaf(psf[pp * 3 + 2], wpe2, bpeh)));
            int gp = g0 + pp;
            qpe[gp * 64 + h]  = aq[p] + pe;
            kpe[gp * 64 + h]  = ak[p] + pe;
            vout[gp * 64 + h] = av[p];
        }
    } else {
        // ---------------- grid build path ----------------
        __shared__ int cnt[512];
        __shared__ int cur[512];
        __shared__ int start[513];

        int s = blockIdx.x - PROJ_BLKS;
        const float* psrc = pos + (size_t)s * N_PTS * 3;

        if (tid < 512) { cnt[tid] = 0; cur[tid] = 0; }
        __syncthreads();

        const float4* g4 = (const float4*)psrc;
        float4 a = g4[tid * 3 + 0];
        float4 b = g4[tid * 3 + 1];
        float4 c4 = g4[tid * 3 + 2];
        float xx[4] = {a.x, a.w, b.z, c4.y};
        float yy[4] = {a.y, b.x, b.w, c4.z};
        float zz[4] = {a.z, b.y, c4.x, c4.w};
        int cell[4];
        #pragma unroll
        for (int k = 0; k < 4; ++k) {
            int cx = min(7, max(0, (int)(xx[k] * 8.0f)));
            int cy = min(7, max(0, (int)(yy[k] * 8.0f)));
            int cz = min(7, max(0, (int)(zz[k] * 8.0f)));
            cell[k] = (cx * 8 + cy) * 8 + cz;
            atomicAdd(&cnt[cell[k]], 1);
        }
        __syncthreads();

        // single-wave exclusive scan of 512 counts
        if (tid < 64) {
            int c[8], pre[8], sum = 0;
            #pragma unroll
            for (int i = 0; i < 8; ++i) {
                c[i] = cnt[tid * 8 + i];
                pre[i] = sum;
                sum += c[i];
            }
            int inc = sum;
            #pragma unroll
            for (int off = 1; off < 64; off <<= 1) {
                int n = __shfl_up(inc, off, 64);
                if (tid >= off) inc += n;
            }
            int excl = inc - sum;
            #pragma unroll
            for (int i = 0; i < 8; ++i) start[tid * 8 + i] = excl + pre[i];
            if (tid == 63) start[512] = N_PTS;
        }
        __syncthreads();

        if (tid < 513) cell_start[s * 513 + tid] = start[tid];

        #pragma unroll
        for (int k = 0; k < 4; ++k) {
            int slot = start[cell[k]] + atomicAdd(&cur[cell[k]], 1);
            gpts[(size_t)s * N_PTS + slot] =
                make_float4(xx[k], yy[k], zz[k],
                            __uint_as_float((unsigned)(tid * 4 + k)));
        }
    }
}

__device__ __forceinline__ float readlane_f(float v, int lane) {
    return __uint_as_float(__builtin_amdgcn_readlane(__float_as_uint(v), lane));
}

// ---------------- Kernel 2: fused exact-top16 + attention ----------------
// One wave per query. Phase 1 (lane = candidate slot): grid-based exact KNN —
// scan (2D+1)^3 cells, ballot-compact d < (D*h)^2 candidates into LDS, then
// rank-count selection; rank-k winners written to a SEPARATE LDS array
// (ridx) to avoid racing reads of mybuf across multi-pass rank loops.
// Keys (dist_bits<<32|idx) reproduce jax.lax.top_k ordering exactly.
// Phase 2 (lane = h): logit merged log-tree reduction (31 shfl), 1 exp/lane
// softmax, PV + Wo projection via v_readlane, GELU, residual.
__global__ __launch_bounds__(512) void knn_attn_kernel(
    const float* __restrict__ x, const float* __restrict__ pos,
    const int* __restrict__ cell_start, const float4* __restrict__ gpts,
    const float* __restrict__ Wpd, const float* __restrict__ bpd,
    const float* __restrict__ Wa, const float* __restrict__ ba,
    const float* __restrict__ Wo, const float* __restrict__ bo,
    const float* __restrict__ qpe, const float* __restrict__ kpe,
    const float* __restrict__ v, float* __restrict__ out)
{
    __shared__ unsigned long long buf[8][CAP];
    __shared__ int ridx[8][KNB];

    int tid = threadIdx.x;
    int wave = tid >> 6, lane = tid & 63;
    int g = blockIdx.x * 8 + wave;
    int s = g >> 12;
    int sbase = s << 12;
    const int* cs = cell_start + s * 513;
    const float4* gp = gpts + (size_t)s * N_PTS;
    unsigned long long* mybuf = buf[wave];

    float qx = pos[g * 3 + 0];
    float qy = pos[g * 3 + 1];
    float qz = pos[g * 3 + 2];
    int cx = min(7, max(0, (int)(qx * 8.0f)));
    int cy = min(7, max(0, (int)(qy * 8.0f)));
    int cz = min(7, max(0, (int)(qz * 8.0f)));
    cx = __builtin_amdgcn_readfirstlane(cx);
    cy = __builtin_amdgcn_readfirstlane(cy);
    cz = __builtin_amdgcn_readfirstlane(cz);

    unsigned long long lanemask_lt = (lane == 0) ? 0ull : (~0ull >> (64 - lane));

    int cnt = 0;
    int D = 1;
    while (true) {
        int xlo = max(cx - D, 0), xhi = min(cx + D, 7);
        int ylo = max(cy - D, 0), yhi = min(cy + D, 7);
        int zlo = max(cz - D, 0), zhi = min(cz + D, 7);
        bool full = (xlo == 0 && ylo == 0 && zlo == 0 &&
                     xhi == 7 && yhi == 7 && zhi == 7);
        float r = (float)D * CELL_H;
        float B = full ? __int_as_float(0x7f800000) : r * r;
        cnt = 0;
        for (int ix = xlo; ix <= xhi; ++ix) {
            for (int iy = ylo; iy <= yhi; ++iy) {
                int base = (ix * 8 + iy) * 8;
                int lo = __builtin_amdgcn_readfirstlane(cs[base + zlo]);
                int hi = __builtin_amdgcn_readfirstlane(cs[base + zhi + 1]);
                for (int bb = lo; bb < hi; bb += 64) {
                    int i = bb + lane;
                    bool act = i < hi;
                    float4 p = gp[act ? i : lo];
                    float dx = qx - p.x, dy = qy - p.y, dz = qz - p.z;
                    float d = fmaf(dx, dx, fmaf(dy, dy, dz * dz));
                    bool pred = act && (d < B);
                    unsigned long long m = __ballot(pred);
                    if (pred) {
                        int slot = cnt + __popcll(m & lanemask_lt);
                        if (slot < CAP)
                            mybuf[slot] =
                                ((unsigned long long)__float_as_uint(d) << 32) |
                                (unsigned long long)__float_as_uint(p.w);
                    }
                    cnt += __popcll(m);
                }
            }
        }
        if (cnt >= KNB || full) break;
        ++D;
    }
    cnt = min(cnt, CAP);

    // rank-count selection into separate ridx array (no mybuf overwrite)
    for (int bb = 0; bb < cnt; bb += 64) {
        int slot = bb + lane;
        unsigned long long my = (slot < cnt) ? mybuf[slot] : ~0ull;
        int rank = 0;
        for (int j = 0; j < cnt; ++j)
            rank += (mybuf[j] < my) ? 1 : 0;
        if (slot < cnt && rank < KNB)
            ridx[wave][rank] = (int)(unsigned)(my & 0xFFFFFFFFull);
    }
    __syncthreads();
    int res = (lane < KNB) ? ridx[wave][lane] : 0;

    // ---------------- Phase 2: attention (lane = h) ----------------
    int h = lane;
    float qv = qpe[g * 64 + h];
    float wh = qv * Wa[h] * 0.125f;   // / sqrt(64)

    float wpd0 = Wpd[0 * 64 + h], wpd1 = Wpd[1 * 64 + h], wpd2 = Wpd[2 * 64 + h];
    float bpdh = bpd[h];

    int jidx[KNB];
    float t[KNB];
    #pragma unroll
    for (int k = 0; k < KNB; ++k) {
        int jj = sbase + __builtin_amdgcn_readlane(res, k);
        jidx[k] = jj;
        float rx = pos[jj * 3 + 0] - qx;
        float ry = pos[jj * 3 + 1] - qy;
        float rz = pos[jj * 3 + 2] - qz;
        float pd = fmaf(rx, wpd0, fmaf(ry, wpd1, fmaf(rz, wpd2, bpdh)));
        t[k] = wh * (kpe[jj * 64 + h] + pd);
    }

    // merged log-tree reduction: 16 vectors reduced with 31 shfl
    #pragma unroll
    for (int kk = 0; kk < 8; ++kk) {
        float a = t[2 * kk]     + __shfl_xor(t[2 * kk],     32, 64);
        float b = t[2 * kk + 1] + __shfl_xor(t[2 * kk + 1], 32, 64);
        t[kk] = (h & 32) ? b : a;
    }
    #pragma unroll
    for (int kk = 0; kk < 4; ++kk) {
        float a = t[2 * kk]     + __shfl_xor(t[2 * kk],     16, 64);
        float b = t[2 * kk + 1] + __shfl_xor(t[2 * kk + 1], 16, 64);
        t[kk] = (h & 16) ? b : a;
    }
    #pragma unroll
    for (int kk = 0; kk < 2; ++kk) {
        float a = t[2 * kk]     + __shfl_xor(t[2 * kk],     8, 64);
        float b = t[2 * kk + 1] + __shfl_xor(t[2 * kk + 1], 8, 64);
        t[kk] = (h & 8) ? b : a;
    }
    {
        float a = t[0] + __shfl_xor(t[0], 4, 64);
        float b = t[1] + __shfl_xor(t[1], 4, 64);
        t[0] = (h & 4) ? b : a;
    }
    float r = t[0];
    r += __shfl_xor(r, 2, 64);
    r += __shfl_xor(r, 1, 64);
    // lane holds logit of k = rev4(lane>>2)

    float lg = r + ba[0];
    float mx = lg;
    mx = fmaxf(mx, __shfl_xor(mx, 4, 64));
    mx = fmaxf(mx, __shfl_xor(mx, 8, 64));
    mx = fmaxf(mx, __shfl_xor(mx, 16, 64));
    mx = fmaxf(mx, __shfl_xor(mx, 32, 64));
    float e = expf(lg - mx);
    float sm = e;
    sm += __shfl_xor(sm, 4, 64);
    sm += __shfl_xor(sm, 8, 64);
    sm += __shfl_xor(sm, 16, 64);
    sm += __shfl_xor(sm, 32, 64);
    float wk_mine = e * (1.0f / sm);

    // PV: broadcast w_k from lane rev4(k)*4 (rev4 is an involution)
    const int rev[KNB] = {0, 8, 4, 12, 2, 10, 6, 14, 1, 9, 5, 13, 3, 11, 7, 15};
    float oh = 0.f;
    #pragma unroll
    for (int k = 0; k < KNB; ++k) {
        float wk = readlane_f(wk_mine, rev[k] << 2);
        oh = fmaf(wk, v[jidx[k] * 64 + h], oh);
    }

    // y_f = bo[f] + sum_h oh[h] * Wo[h][f]   (lane == f), via readlane
    float y = bo[h];
    #pragma unroll
    for (int hh = 0; hh < 64; ++hh) {
        float o = readlane_f(oh, hh);
        y = fmaf(o, Wo[hh * 64 + h], y);
    }

    // tanh-approx GELU (JAX default approximate=True)
    float t3 = y + 0.044715f * y * y * y;
    float ge = 0.5f * y * (1.0f + tanhf(0.7978845608028654f * t3));

    out[g * 64 + h] = x[g * 64 + h] + ge;
}

extern "C" void kernel_launch(void* const* d_in, const int* in_sizes, int n_in,
                              void* d_out, int out_size, void* d_ws, size_t ws_size,
                              hipStream_t stream) {
    const float* x   = (const float*)d_in[0];
    const float* pos = (const float*)d_in[1];
    const float* Wq  = (const float*)d_in[2];
    const float* bq  = (const float*)d_in[3];
    const float* Wk  = (const float*)d_in[4];
    const float* bk  = (const float*)d_in[5];
    const float* Wv  = (const float*)d_in[6];
    const float* bv  = (const float*)d_in[7];
    const float* Wpe = (const float*)d_in[8];
    const float* bpe = (const float*)d_in[9];
    const float* Wpd = (const float*)d_in[10];
    const float* bpd = (const float*)d_in[11];
    const float* Wa  = (const float*)d_in[12];
    const float* ba  = (const float*)d_in[13];
    const float* Wo  = (const float*)d_in[14];
    const float* bo  = (const float*)d_in[15];
    float* out = (float*)d_out;

    float* ws  = (float*)d_ws;
    float* qpe = ws;
    float* kpe = ws + (size_t)P_TOT * 64;
    float* vv  = ws + (size_t)2 * P_TOT * 64;
    int*   cstart = (int*)(ws + (size_t)3 * P_TOT * 64);        // 4*513 ints
    float4* gpts = (float4*)(cstart + 4 * 513 + 3);             // 16B-aligned

    pre_kernel<<<PROJ_BLKS + S_DIM, 1024, 0, stream>>>(
        x, pos, Wq, bq, Wk, bk, Wv, bv, Wpe, bpe, qpe, kpe, vv, cstart, gpts);
    knn_attn_kernel<<<P_TOT / 8, 512, 0, stream>>>(
        x, pos, cstart, gpts, Wpd, bpd, Wa, ba, Wo, bo, qpe, kpe, vv, out);
}

// Round 7
// 79.581 us; speedup vs baseline: 1.2276x; 1.2276x over previous
//
#include <hip/hip_runtime.h>
#include <hip/hip_bf16.h>

#define S_DIM 4
#define N_PTS 4096
#define P_TOT (S_DIM * N_PTS)   // 16384
#define HID 64
#define KNB 16

#define CELL_H 0.125f
#define CAP 352                  // per-wave candidate buffer (LDS)
#define PROJ_BLKS 256            // 64 points per block, 4 per wave

// ---------------- Kernel 1: fused projections + grid build ----------------
// blocks [0, PROJ_BLKS): qpe/kpe/v projections, 64 points per block,
//   register-blocked 4 points per wave.
// blocks [PROJ_BLKS, PROJ_BLKS+S_DIM): per-scene 8^3 cell grid build.
__global__ __launch_bounds__(1024) void pre_kernel(
    const float* __restrict__ x, const float* __restrict__ pos,
    const float* __restrict__ Wq, const float* __restrict__ bq,
    const float* __restrict__ Wk, const float* __restrict__ bk,
    const float* __restrict__ Wv, const float* __restrict__ bv,
    const float* __restrict__ Wpe, const float* __restrict__ bpe,
    float* __restrict__ qpe, float* __restrict__ kpe, float* __restrict__ vout,
    int* __restrict__ cell_start, float4* __restrict__ gpts)
{
    int tid = threadIdx.x;

    if (blockIdx.x < PROJ_BLKS) {
        // ---------------- projection path ----------------
        __shared__ float xs[64][64];     // 16 KB
        __shared__ float psf[192];       // 64 pts x 3
        int h = tid & 63;
        int wv = tid >> 6;               // wave 0..15
        int g0 = blockIdx.x * 64;

        ((float4*)xs)[tid] = ((const float4*)(x + (size_t)g0 * 64))[tid];
        if (tid < 48)
            ((float4*)psf)[tid] = ((const float4*)(pos + (size_t)g0 * 3))[tid];
        __syncthreads();

        int pbase = wv * 4;
        float aq[4], ak[4], av[4];
        #pragma unroll
        for (int p = 0; p < 4; ++p) { aq[p] = bq[h]; ak[p] = bk[h]; av[p] = bv[h]; }

        #pragma unroll 8
        for (int f = 0; f < 64; ++f) {
            float wq = Wq[f * 64 + h];
            float wk = Wk[f * 64 + h];
            float wvv = Wv[f * 64 + h];
            #pragma unroll
            for (int p = 0; p < 4; ++p) {
                float xf = xs[pbase + p][f];
                aq[p] = fmaf(xf, wq, aq[p]);
                ak[p] = fmaf(xf, wk, ak[p]);
                av[p] = fmaf(xf, wvv, av[p]);
            }
        }

        float wpe0 = Wpe[0 * 64 + h], wpe1 = Wpe[1 * 64 + h], wpe2 = Wpe[2 * 64 + h];
        float bpeh = bpe[h];
        #pragma unroll
        for (int p = 0; p < 4; ++p) {
            int pp = pbase + p;
            float pe = fmaf(psf[pp * 3 + 0], wpe0,
                       fmaf(psf[pp * 3 + 1], wpe1,
                       fmaf(psf[pp * 3 + 2], wpe2, bpeh)));
            int gp = g0 + pp;
            qpe[gp * 64 + h]  = aq[p] + pe;
            kpe[gp * 64 + h]  = ak[p] + pe;
            vout[gp * 64 + h] = av[p];
        }
    } else {
        // ---------------- grid build path ----------------
        __shared__ int cnt[512];
        __shared__ int cur[512];
        __shared__ int start[513];

        int s = blockIdx.x - PROJ_BLKS;
        const float* psrc = pos + (size_t)s * N_PTS * 3;

        if (tid < 512) { cnt[tid] = 0; cur[tid] = 0; }
        __syncthreads();

        const float4* g4 = (const float4*)psrc;
        float4 a = g4[tid * 3 + 0];
        float4 b = g4[tid * 3 + 1];
        float4 c4 = g4[tid * 3 + 2];
        float xx[4] = {a.x, a.w, b.z, c4.y};
        float yy[4] = {a.y, b.x, b.w, c4.z};
        float zz[4] = {a.z, b.y, c4.x, c4.w};
        int cell[4];
        #pragma unroll
        for (int k = 0; k < 4; ++k) {
            int cx = min(7, max(0, (int)(xx[k] * 8.0f)));
            int cy = min(7, max(0, (int)(yy[k] * 8.0f)));
            int cz = min(7, max(0, (int)(zz[k] * 8.0f)));
            cell[k] = (cx * 8 + cy) * 8 + cz;
            atomicAdd(&cnt[cell[k]], 1);
        }
        __syncthreads();

        // single-wave exclusive scan of 512 counts
        if (tid < 64) {
            int c[8], pre[8], sum = 0;
            #pragma unroll
            for (int i = 0; i < 8; ++i) {
                c[i] = cnt[tid * 8 + i];
                pre[i] = sum;
                sum += c[i];
            }
            int inc = sum;
            #pragma unroll
            for (int off = 1; off < 64; off <<= 1) {
                int n = __shfl_up(inc, off, 64);
                if (tid >= off) inc += n;
            }
            int excl = inc - sum;
            #pragma unroll
            for (int i = 0; i < 8; ++i) start[tid * 8 + i] = excl + pre[i];
            if (tid == 63) start[512] = N_PTS;
        }
        __syncthreads();

        if (tid < 513) cell_start[s * 513 + tid] = start[tid];

        #pragma unroll
        for (int k = 0; k < 4; ++k) {
            int slot = start[cell[k]] + atomicAdd(&cur[cell[k]], 1);
            gpts[(size_t)s * N_PTS + slot] =
                make_float4(xx[k], yy[k], zz[k],
                            __uint_as_float((unsigned)(tid * 4 + k)));
        }
    }
}

__device__ __forceinline__ float readlane_f(float v, int lane) {
    return __uint_as_float(__builtin_amdgcn_readlane(__float_as_uint(v), lane));
}

// ---------------- Kernel 2: fused exact-top16 + attention ----------------
// One wave per query, queries taken in GRID-SORTED order (slot in gpts) with
// an XCD-chunk block swizzle so co-resident waves gather from overlapping
// regions. Phase 1: D=1 fast path packs the 9 z-column runs into dense
// 64-lane ballot iterations; candidates with d < (D*h)^2 compacted into LDS;
// rank-count selection (order-independent, keys (dist<<32|idx) reproduce
// jax.lax.top_k exactly). Rare D>=2 growth falls back to nested scan.
// Phase 2 (lane = h): merged log-tree logit reduction, 1 exp/lane softmax,
// PV + Wo via v_readlane, GELU, residual. No block-wide barriers: ridx
// write->read ordering enforced by wave-local s_waitcnt lgkmcnt(0).
__global__ __launch_bounds__(512) void knn_attn_kernel(
    const float* __restrict__ x, const float* __restrict__ pos,
    const int* __restrict__ cell_start, const float4* __restrict__ gpts,
    const float* __restrict__ Wpd, const float* __restrict__ bpd,
    const float* __restrict__ Wa, const float* __restrict__ ba,
    const float* __restrict__ Wo, const float* __restrict__ bo,
    const float* __restrict__ qpe, const float* __restrict__ kpe,
    const float* __restrict__ v, float* __restrict__ out)
{
    __shared__ unsigned long long buf[8][CAP];
    __shared__ int ridx[8][KNB];

    int tid = threadIdx.x;
    int wave = tid >> 6, lane = tid & 63;

    // bijective XCD-chunk swizzle: 2048 blocks, 8 XCDs -> 256-block chunks
    int bid = blockIdx.x;
    int swz = (bid & 7) * 256 + (bid >> 3);
    int qslot = swz * 8 + wave;              // slot in grid-sorted order
    int s = qslot >> 12;
    int sbase = s << 12;
    const int* cs = cell_start + s * 513;
    const float4* gp = gpts + (size_t)sbase;
    unsigned long long* mybuf = buf[wave];

    float4 q4 = gp[qslot & 4095];
    float qx = q4.x, qy = q4.y, qz = q4.z;
    int g = sbase + (int)__float_as_uint(q4.w);

    int cx = min(7, max(0, (int)(qx * 8.0f)));
    int cy = min(7, max(0, (int)(qy * 8.0f)));
    int cz = min(7, max(0, (int)(qz * 8.0f)));
    cx = __builtin_amdgcn_readfirstlane(cx);
    cy = __builtin_amdgcn_readfirstlane(cy);
    cz = __builtin_amdgcn_readfirstlane(cz);

    unsigned long long lanemask_lt = (lane == 0) ? 0ull : (~0ull >> (64 - lane));

    // ---------- Phase 1 fast path: D=1, packed 9-run scan ----------
    int cnt = 0;
    {
        int zlo = max(cz - 1, 0), zhi = min(cz + 1, 7);
        int P[10], LO[9];
        P[0] = 0;
        #pragma unroll
        for (int rr = 0; rr < 9; ++rr) {
            int ix = cx - 1 + rr / 3;
            int iy = cy - 1 + rr % 3;
            bool valid = (ix >= 0 && ix <= 7 && iy >= 0 && iy <= 7);
            int base = (ix * 8 + iy) * 8;
            int lo = valid ? cs[base + zlo] : 0;
            int hi = valid ? cs[base + zhi + 1] : 0;
            lo = __builtin_amdgcn_readfirstlane(lo);
            hi = __builtin_amdgcn_readfirstlane(hi);
            LO[rr] = lo;
            P[rr + 1] = P[rr] + max(hi - lo, 0);
        }
        int T = P[9];
        float B = CELL_H * CELL_H;
        for (int p0 = 0; p0 < T; p0 += 64) {
            int pidx = p0 + lane;
            int src = LO[0] + pidx;
            #pragma unroll
            for (int t = 1; t < 9; ++t)
                src = (pidx >= P[t]) ? (LO[t] + pidx - P[t]) : src;
            src = min(src, N_PTS - 1);
            bool act = pidx < T;
            float4 p = gp[src];
            float dx = qx - p.x, dy = qy - p.y, dz = qz - p.z;
            float d = fmaf(dx, dx, fmaf(dy, dy, dz * dz));
            bool pred = act && (d < B);
            unsigned long long m = __ballot(pred);
            if (pred) {
                int slot = cnt + __popcll(m & lanemask_lt);
                if (slot < CAP)
                    mybuf[slot] =
                        ((unsigned long long)__float_as_uint(d) << 32) |
                        (unsigned long long)__float_as_uint(p.w);
            }
            cnt += __popcll(m);
        }
    }

    // ---------- rare fallback: grow D ----------
    if (cnt < KNB) {
        int D = 2;
        while (true) {
            int xlo = max(cx - D, 0), xhi = min(cx + D, 7);
            int ylo = max(cy - D, 0), yhi = min(cy + D, 7);
            int zlo = max(cz - D, 0), zhi = min(cz + D, 7);
            bool full = (xlo == 0 && ylo == 0 && zlo == 0 &&
                         xhi == 7 && yhi == 7 && zhi == 7);
            float r = (float)D * CELL_H;
            float B = full ? __int_as_float(0x7f800000) : r * r;
            cnt = 0;
            for (int ix = xlo; ix <= xhi; ++ix) {
                for (int iy = ylo; iy <= yhi; ++iy) {
                    int base = (ix * 8 + iy) * 8;
                    int lo = __builtin_amdgcn_readfirstlane(cs[base + zlo]);
                    int hi = __builtin_amdgcn_readfirstlane(cs[base + zhi + 1]);
                    for (int bb = lo; bb < hi; bb += 64) {
                        int i = bb + lane;
                        bool act = i < hi;
                        float4 p = gp[act ? i : lo];
                        float dx = qx - p.x, dy = qy - p.y, dz = qz - p.z;
                        float d = fmaf(dx, dx, fmaf(dy, dy, dz * dz));
                        bool pred = act && (d < B);
                        unsigned long long m = __ballot(pred);
                        if (pred) {
                            int slot = cnt + __popcll(m & lanemask_lt);
                            if (slot < CAP)
                                mybuf[slot] =
                                    ((unsigned long long)__float_as_uint(d) << 32) |
                                    (unsigned long long)__float_as_uint(p.w);
                        }
                        cnt += __popcll(m);
                    }
                }
            }
            if (cnt >= KNB || full) break;
            ++D;
        }
    }
    cnt = min(cnt, CAP);

    // ensure all compaction writes (by any lane of this wave) are visible
    __builtin_amdgcn_wave_barrier();
    asm volatile("s_waitcnt lgkmcnt(0)" ::: "memory");

    // rank-count selection into separate ridx array
    for (int bb = 0; bb < cnt; bb += 64) {
        int slot = bb + lane;
        unsigned long long my = (slot < cnt) ? mybuf[slot] : ~0ull;
        int rank = 0;
        for (int j = 0; j < cnt; ++j)
            rank += (mybuf[j] < my) ? 1 : 0;
        if (slot < cnt && rank < KNB)
            ridx[wave][rank] = (int)(unsigned)(my & 0xFFFFFFFFull);
    }
    __builtin_amdgcn_wave_barrier();
    asm volatile("s_waitcnt lgkmcnt(0)" ::: "memory");
    int res = (lane < KNB) ? ridx[wave][lane] : 0;

    // ---------------- Phase 2: attention (lane = h) ----------------
    int h = lane;
    float qv = qpe[g * 64 + h];
    float wh = qv * Wa[h] * 0.125f;   // / sqrt(64)

    float wpd0 = Wpd[0 * 64 + h], wpd1 = Wpd[1 * 64 + h], wpd2 = Wpd[2 * 64 + h];
    float bpdh = bpd[h];

    int jidx[KNB];
    float t[KNB];
    #pragma unroll
    for (int k = 0; k < KNB; ++k) {
        int jj = sbase + __builtin_amdgcn_readlane(res, k);
        jidx[k] = jj;
        float rx = pos[jj * 3 + 0] - qx;
        float ry = pos[jj * 3 + 1] - qy;
        float rz = pos[jj * 3 + 2] - qz;
        float pd = fmaf(rx, wpd0, fmaf(ry, wpd1, fmaf(rz, wpd2, bpdh)));
        t[k] = wh * (kpe[jj * 64 + h] + pd);
    }

    // merged log-tree reduction: 16 vectors reduced with 31 shfl
    #pragma unroll
    for (int kk = 0; kk < 8; ++kk) {
        float a = t[2 * kk]     + __shfl_xor(t[2 * kk],     32, 64);
        float b = t[2 * kk + 1] + __shfl_xor(t[2 * kk + 1], 32, 64);
        t[kk] = (h & 32) ? b : a;
    }
    #pragma unroll
    for (int kk = 0; kk < 4; ++kk) {
        float a = t[2 * kk]     + __shfl_xor(t[2 * kk],     16, 64);
        float b = t[2 * kk + 1] + __shfl_xor(t[2 * kk + 1], 16, 64);
        t[kk] = (h & 16) ? b : a;
    }
    #pragma unroll
    for (int kk = 0; kk < 2; ++kk) {
        float a = t[2 * kk]     + __shfl_xor(t[2 * kk],     8, 64);
        float b = t[2 * kk + 1] + __shfl_xor(t[2 * kk + 1], 8, 64);
        t[kk] = (h & 8) ? b : a;
    }
    {
        float a = t[0] + __shfl_xor(t[0], 4, 64);
        float b = t[1] + __shfl_xor(t[1], 4, 64);
        t[0] = (h & 4) ? b : a;
    }
    float r = t[0];
    r += __shfl_xor(r, 2, 64);
    r += __shfl_xor(r, 1, 64);
    // lane holds logit of k = rev4(lane>>2)

    float lg = r + ba[0];
    float mx = lg;
    mx = fmaxf(mx, __shfl_xor(mx, 4, 64));
    mx = fmaxf(mx, __shfl_xor(mx, 8, 64));
    mx = fmaxf(mx, __shfl_xor(mx, 16, 64));
    mx = fmaxf(mx, __shfl_xor(mx, 32, 64));
    float e = expf(lg - mx);
    float sm = e;
    sm += __shfl_xor(sm, 4, 64);
    sm += __shfl_xor(sm, 8, 64);
    sm += __shfl_xor(sm, 16, 64);
    sm += __shfl_xor(sm, 32, 64);
    float wk_mine = e * (1.0f / sm);

    // PV: broadcast w_k from lane rev4(k)*4 (rev4 is an involution)
    const int rev[KNB] = {0, 8, 4, 12, 2, 10, 6, 14, 1, 9, 5, 13, 3, 11, 7, 15};
    float oh = 0.f;
    #pragma unroll
    for (int k = 0; k < KNB; ++k) {
        float wk = readlane_f(wk_mine, rev[k] << 2);
        oh = fmaf(wk, v[jidx[k] * 64 + h], oh);
    }

    // y_f = bo[f] + sum_h oh[h] * Wo[h][f]   (lane == f), via readlane
    float y = bo[h];
    #pragma unroll
    for (int hh = 0; hh < 64; ++hh) {
        float o = readlane_f(oh, hh);
        y = fmaf(o, Wo[hh * 64 + h], y);
    }

    // tanh-approx GELU (JAX default approximate=True)
    float t3 = y + 0.044715f * y * y * y;
    float ge = 0.5f * y * (1.0f + tanhf(0.7978845608028654f * t3));

    out[g * 64 + h] = x[g * 64 + h] + ge;
}

extern "C" void kernel_launch(void* const* d_in, const int* in_sizes, int n_in,
                              void* d_out, int out_size, void* d_ws, size_t ws_size,
                              hipStream_t stream) {
    const float* x   = (const float*)d_in[0];
    const float* pos = (const float*)d_in[1];
    const float* Wq  = (const float*)d_in[2];
    const float* bq  = (const float*)d_in[3];
    const float* Wk  = (const float*)d_in[4];
    const float* bk  = (const float*)d_in[5];
    const float* Wv  = (const float*)d_in[6];
    const float* bv  = (const float*)d_in[7];
    const float* Wpe = (const float*)d_in[8];
    const float* bpe = (const float*)d_in[9];
    const float* Wpd = (const float*)d_in[10];
    const float* bpd = (const float*)d_in[11];
    const float* Wa  = (const float*)d_in[12];
    const float* ba  = (const float*)d_in[13];
    const float* Wo  = (const float*)d_in[14];
    const float* bo  = (const float*)d_in[15];
    float* out = (float*)d_out;

    float* ws  = (float*)d_ws;
    float* qpe = ws;
    float* kpe = ws + (size_t)P_TOT * 64;
    float* vv  = ws + (size_t)2 * P_TOT * 64;
    int*   cstart = (int*)(ws + (size_t)3 * P_TOT * 64);        // 4*513 ints
    float4* gpts = (float4*)(cstart + 4 * 513 + 3);             // 16B-aligned

    pre_kernel<<<PROJ_BLKS + S_DIM, 1024, 0, stream>>>(
        x, pos, Wq, bq, Wk, bk, Wv, bv, Wpe, bpe, qpe, kpe, vv, cstart, gpts);
    knn_attn_kernel<<<P_TOT / 8, 512, 0, stream>>>(
        x, pos, cstart, gpts, Wpd, bpd, Wa, ba, Wo, bo, qpe, kpe, vv, out);
}

// Round 8
// 59.990 us; speedup vs baseline: 1.6285x; 1.3266x over previous
//
#include <hip/hip_runtime.h>
#include <hip/hip_bf16.h>

#define S_DIM 4
#define N_PTS 4096
#define P_TOT (S_DIM * N_PTS)   // 16384
#define KNB 16

#define GD 16                    // grid dim per axis
#define NCELL (GD * GD * GD)     // 4096
#define CSTRIDE (NCELL + 1)
#define CAP 224                  // per-wave candidate buffer
#define MAXRUN 256               // max z-columns per query
#define PROJ_BLKS 256            // 64 points per block, 4 per wave

// ---------------- Kernel 1: fused projections + grid build ----------------
__global__ __launch_bounds__(1024) void pre_kernel(
    const float* __restrict__ x, const float* __restrict__ pos,
    const float* __restrict__ Wq, const float* __restrict__ bq,
    const float* __restrict__ Wk, const float* __restrict__ bk,
    const float* __restrict__ Wv, const float* __restrict__ bv,
    const float* __restrict__ Wpe, const float* __restrict__ bpe,
    float* __restrict__ qpe, float* __restrict__ kpe, float* __restrict__ vout,
    int* __restrict__ cell_start, float4* __restrict__ gpts)
{
    int tid = threadIdx.x;

    if (blockIdx.x < PROJ_BLKS) {
        // ---------------- projection path ----------------
        __shared__ float xs[64][64];     // 16 KB
        __shared__ float psf[192];
        int h = tid & 63;
        int wv = tid >> 6;
        int g0 = blockIdx.x * 64;

        ((float4*)xs)[tid] = ((const float4*)(x + (size_t)g0 * 64))[tid];
        if (tid < 48)
            ((float4*)psf)[tid] = ((const float4*)(pos + (size_t)g0 * 3))[tid];
        __syncthreads();

        int pbase = wv * 4;
        float aq[4], ak[4], av[4];
        #pragma unroll
        for (int p = 0; p < 4; ++p) { aq[p] = bq[h]; ak[p] = bk[h]; av[p] = bv[h]; }

        #pragma unroll 8
        for (int f = 0; f < 64; ++f) {
            float wq = Wq[f * 64 + h];
            float wk = Wk[f * 64 + h];
            float wvv = Wv[f * 64 + h];
            #pragma unroll
            for (int p = 0; p < 4; ++p) {
                float xf = xs[pbase + p][f];
                aq[p] = fmaf(xf, wq, aq[p]);
                ak[p] = fmaf(xf, wk, ak[p]);
                av[p] = fmaf(xf, wvv, av[p]);
            }
        }

        float wpe0 = Wpe[0 * 64 + h], wpe1 = Wpe[1 * 64 + h], wpe2 = Wpe[2 * 64 + h];
        float bpeh = bpe[h];
        #pragma unroll
        for (int p = 0; p < 4; ++p) {
            int pp = pbase + p;
            float pe = fmaf(psf[pp * 3 + 0], wpe0,
                       fmaf(psf[pp * 3 + 1], wpe1,
                       fmaf(psf[pp * 3 + 2], wpe2, bpeh)));
            int gp = g0 + pp;
            qpe[gp * 64 + h]  = aq[p] + pe;
            kpe[gp * 64 + h]  = ak[p] + pe;
            vout[gp * 64 + h] = av[p];
        }
    } else {
        // ---------------- 16^3 grid build path ----------------
        __shared__ int cnt[NCELL];       // 16 KB
        __shared__ int start[NCELL + 1]; // 16 KB
        __shared__ int wtot[16];

        int s = blockIdx.x - PROJ_BLKS;
        const float* psrc = pos + (size_t)s * N_PTS * 3;

        for (int i = tid; i < NCELL; i += 1024) cnt[i] = 0;
        __syncthreads();

        const float4* g4 = (const float4*)psrc;
        float4 a = g4[tid * 3 + 0];
        float4 b = g4[tid * 3 + 1];
        float4 c4 = g4[tid * 3 + 2];
        float xx[4] = {a.x, a.w, b.z, c4.y};
        float yy[4] = {a.y, b.x, b.w, c4.z};
        float zz[4] = {a.z, b.y, c4.x, c4.w};
        int cell[4];
        #pragma unroll
        for (int k = 0; k < 4; ++k) {
            int cx = min(GD - 1, max(0, (int)(xx[k] * 16.0f)));
            int cy = min(GD - 1, max(0, (int)(yy[k] * 16.0f)));
            int cz = min(GD - 1, max(0, (int)(zz[k] * 16.0f)));
            cell[k] = (cx * GD + cy) * GD + cz;
            atomicAdd(&cnt[cell[k]], 1);
        }
        __syncthreads();

        // hierarchical exclusive scan of 4096 counts
        int wv = tid >> 6, lane = tid & 63;
        int c0 = cnt[tid * 4 + 0], c1 = cnt[tid * 4 + 1];
        int c2 = cnt[tid * 4 + 2], c3 = cnt[tid * 4 + 3];
        int ts = c0 + c1 + c2 + c3;
        int inc = ts;
        #pragma unroll
        for (int off = 1; off < 64; off <<= 1) {
            int n = __shfl_up(inc, off, 64);
            if (lane >= off) inc += n;
        }
        if (lane == 63) wtot[wv] = inc;
        __syncthreads();
        if (wv == 0) {
            int v0 = (lane < 16) ? wtot[lane] : 0;
            int i2 = v0;
            #pragma unroll
            for (int off = 1; off < 16; off <<= 1) {
                int n = __shfl_up(i2, off, 64);
                if (lane >= off) i2 += n;
            }
            if (lane < 16) wtot[lane] = i2 - v0;   // exclusive
        }
        __syncthreads();
        int base = wtot[wv] + inc - ts;
        start[tid * 4 + 0] = base;
        start[tid * 4 + 1] = base + c0;
        start[tid * 4 + 2] = base + c0 + c1;
        start[tid * 4 + 3] = base + c0 + c1 + c2;
        if (tid == 0) start[NCELL] = N_PTS;
        __syncthreads();

        for (int i = tid; i < NCELL + 1; i += 1024)
            cell_start[s * CSTRIDE + i] = start[i];
        for (int i = tid; i < NCELL; i += 1024) cnt[i] = 0;   // reuse as cursor
        __syncthreads();

        #pragma unroll
        for (int k = 0; k < 4; ++k) {
            int slot = start[cell[k]] + atomicAdd(&cnt[cell[k]], 1);
            gpts[(size_t)s * N_PTS + slot] =
                make_float4(xx[k], yy[k], zz[k],
                            __uint_as_float((unsigned)(tid * 4 + k)));
        }
    }
}

__device__ __forceinline__ float readlane_f(float v, int lane) {
    return __uint_as_float(__builtin_amdgcn_readlane(__float_as_uint(v), lane));
}

// ---------------- Kernel 2: fused exact-top16 + attention ----------------
// One wave per query (grid-sorted order + XCD swizzle). Phase 1: adaptive
// radius r (target ~40 candidates incl. boundary truncation), enumerate only
// z-column runs intersecting ball(r) via wave-parallel run-table build (LDS)
// + binary-search gather; ballot-compact d<r^2 keys (dist<<32|origidx) into
// LDS; rank-count selection (exact jax.lax.top_k order). Safety loop
// grows/shrinks r if cnt outside [16,CAP]. Phase 2 (lane=h): merged log-tree
// logit reduction, 1 exp/lane softmax, PV via readlane, Wo via LDS float4
// reads, GELU, residual.
__global__ __launch_bounds__(512) void knn_attn_kernel(
    const float* __restrict__ x, const float* __restrict__ pos,
    const int* __restrict__ cell_start, const float4* __restrict__ gpts,
    const float* __restrict__ Wpd, const float* __restrict__ bpd,
    const float* __restrict__ Wa, const float* __restrict__ ba,
    const float* __restrict__ Wo, const float* __restrict__ bo,
    const float* __restrict__ qpe, const float* __restrict__ kpe,
    const float* __restrict__ v, float* __restrict__ out)
{
    __shared__ unsigned long long buf[8][CAP];   // 14 KB
    __shared__ int Ptab[8][MAXRUN + 1];          // 8.2 KB
    __shared__ int LOtab[8][MAXRUN];             // 8 KB
    __shared__ int ridx[8][KNB];
    __shared__ float ohs[8][64];

    int tid = threadIdx.x;
    int wave = tid >> 6, lane = tid & 63;

    int bid = blockIdx.x;
    int swz = (bid & 7) * 256 + (bid >> 3);      // bijective XCD swizzle
    int qslot = swz * 8 + wave;
    int s = qslot >> 12;
    int sbase = s << 12;
    const int* cs = cell_start + s * CSTRIDE;
    const float4* gp = gpts + (size_t)sbase;
    unsigned long long* mybuf = buf[wave];
    int* Pw = Ptab[wave];
    int* Lw = LOtab[wave];

    float4 q4 = gp[qslot & (N_PTS - 1)];
    float qx = q4.x, qy = q4.y, qz = q4.z;
    int g = sbase + (int)__float_as_uint(q4.w);

    // ---- adaptive radius: target ~40 candidates after boundary truncation
    float bx = fminf(qx, 1.f - qx), by = fminf(qy, 1.f - qy), bz = fminf(qz, 1.f - qz);
    float r = 0.125f;
    #pragma unroll
    for (int it = 0; it < 2; ++it) {
        float ux = fminf(bx / r, 1.f), uy = fminf(by / r, 1.f), uz = fminf(bz / r, 1.f);
        float fx = 0.5f + 0.75f * ux - 0.25f * ux * ux * ux;
        float fy = 0.5f + 0.75f * uy - 0.25f * uy * uy * uy;
        float fz = 0.5f + 0.75f * uz - 0.25f * uz * uz * uz;
        float est = 17157.3f * r * r * r * fx * fy * fz;
        float sc = exp2f(0.3333333f * log2f(40.f / est));
        r = fminf(fmaxf(r * sc, 0.09f), 0.32f);
    }
    r = __uint_as_float(__builtin_amdgcn_readfirstlane(__float_as_uint(r)));

    unsigned long long lanemask_lt = (lane == 0) ? 0ull : (~0ull >> (64 - lane));

    int cnt = 0;
    for (int tries = 0; tries < 6; ++tries) {
        float B = r * r;
        float Bc = B * 1.0002f + 1e-7f;   // conservative cull bound
        int xlo = max(0, (int)floorf((qx - r) * 16.f - 1e-4f));
        int xhi = min(GD - 1, (int)floorf((qx + r) * 16.f + 1e-4f));
        int ylo = max(0, (int)floorf((qy - r) * 16.f - 1e-4f));
        int yhi = min(GD - 1, (int)floorf((qy + r) * 16.f + 1e-4f));
        int nx = xhi - xlo + 1, ny = yhi - ylo + 1;
        int NC = __builtin_amdgcn_readfirstlane(nx * ny);
        float rcp_ny = 1.f / (float)ny;

        // ---- wave-parallel run-table build (per-lane column)
        int carry = 0;
        for (int c0 = 0; c0 < NC; c0 += 64) {
            int cidx = c0 + lane;
            bool vld = cidx < NC;
            int qd = (int)(((float)cidx + 0.5f) * rcp_ny);
            int iy = ylo + (cidx - qd * ny);
            int ix = xlo + qd;
            float x0 = (float)ix * 0.0625f;
            float ax = fmaxf(0.f, fmaxf(x0 - qx, qx - (x0 + 0.0625f)));
            float y0 = (float)iy * 0.0625f;
            float ay = fmaxf(0.f, fmaxf(y0 - qy, qy - (y0 + 0.0625f)));
            float rem = Bc - ax * ax - ay * ay;
            int lo = 0, len = 0;
            if (vld && rem > 0.f) {
                float zs = sqrtf(rem) + 1e-4f;
                int zl = max(0, (int)floorf((qz - zs) * 16.f));
                int zh = min(GD - 1, (int)floorf((qz + zs) * 16.f));
                int cb = (ix * GD + iy) * GD;
                lo = cs[cb + zl];
                len = cs[cb + zh + 1] - lo;
            }
            int inc = len;
            #pragma unroll
            for (int off = 1; off < 64; off <<= 1) {
                int n = __shfl_up(inc, off, 64);
                if (lane >= off) inc += n;
            }
            int excl = carry + inc - len;
            if (vld) { Pw[cidx] = excl; Lw[cidx] = lo - excl; }
            carry += __builtin_amdgcn_readlane(inc, 63);
        }
        if (lane == 0) Pw[NC] = carry;
        int T = carry;
        __builtin_amdgcn_wave_barrier();
        asm volatile("s_waitcnt lgkmcnt(0)" ::: "memory");

        // ---- gather + compact
        cnt = 0;
        for (int p0 = 0; p0 < T; p0 += 64) {
            int pidx = p0 + lane;
            bool act = pidx < T;
            int blo = 0, bhi = NC;
            #pragma unroll
            for (int bs = 0; bs < 8; ++bs) {
                int mid = (blo + bhi) >> 1;
                int pm = Pw[mid];
                bool cge = pidx >= pm;
                blo = cge ? mid : blo;
                bhi = cge ? bhi : mid;
            }
            int src = act ? (Lw[blo] + pidx) : 0;
            float4 p = gp[src];
            float dx = qx - p.x, dy = qy - p.y, dz = qz - p.z;
            float d = fmaf(dx, dx, fmaf(dy, dy, dz * dz));
            bool pred = act && (d < B);
            unsigned long long m = __ballot(pred);
            if (pred) {
                int slot = cnt + __popcll(m & lanemask_lt);
                if (slot < CAP)
                    mybuf[slot] =
                        ((unsigned long long)__float_as_uint(d) << 32) |
                        (unsigned long long)__float_as_uint(p.w);
            }
            cnt += __popcll(m);
        }
        if (cnt >= KNB && cnt <= CAP) break;
        r = (cnt < KNB) ? r * 1.35f : r * 0.72f;
    }
    cnt = min(cnt, CAP);

    __builtin_amdgcn_wave_barrier();
    asm volatile("s_waitcnt lgkmcnt(0)" ::: "memory");

    // ---- rank-count selection (exact top-k order)
    if (lane < KNB) ridx[wave][lane] = 0;
    for (int bb = 0; bb < cnt; bb += 64) {
        int slot = bb + lane;
        unsigned long long my = (slot < cnt) ? mybuf[slot] : ~0ull;
        int rank = 0;
        for (int j = 0; j < cnt; ++j)
            rank += (mybuf[j] < my) ? 1 : 0;
        if (slot < cnt && rank < KNB)
            ridx[wave][rank] = (int)(unsigned)(my & 0xFFFFFFFFull);
    }
    __builtin_amdgcn_wave_barrier();
    asm volatile("s_waitcnt lgkmcnt(0)" ::: "memory");
    int res = (lane < KNB) ? ridx[wave][lane] : 0;

    // ---------------- Phase 2: attention (lane = h) ----------------
    int h = lane;
    float qv = qpe[g * 64 + h];
    float wh = qv * Wa[h] * 0.125f;   // / sqrt(64)

    float wpd0 = Wpd[0 * 64 + h], wpd1 = Wpd[1 * 64 + h], wpd2 = Wpd[2 * 64 + h];
    float bpdh = bpd[h];

    int jidx[KNB];
    float t[KNB];
    #pragma unroll
    for (int k = 0; k < KNB; ++k) {
        int jj = sbase + __builtin_amdgcn_readlane(res, k);
        jidx[k] = jj;
        float rx = pos[jj * 3 + 0] - qx;
        float ry = pos[jj * 3 + 1] - qy;
        float rz = pos[jj * 3 + 2] - qz;
        float pd = fmaf(rx, wpd0, fmaf(ry, wpd1, fmaf(rz, wpd2, bpdh)));
        t[k] = wh * (kpe[jj * 64 + h] + pd);
    }

    // merged log-tree reduction: 16 vectors reduced with 31 shfl
    #pragma unroll
    for (int kk = 0; kk < 8; ++kk) {
        float a = t[2 * kk]     + __shfl_xor(t[2 * kk],     32, 64);
        float b = t[2 * kk + 1] + __shfl_xor(t[2 * kk + 1], 32, 64);
        t[kk] = (h & 32) ? b : a;
    }
    #pragma unroll
    for (int kk = 0; kk < 4; ++kk) {
        float a = t[2 * kk]     + __shfl_xor(t[2 * kk],     16, 64);
        float b = t[2 * kk + 1] + __shfl_xor(t[2 * kk + 1], 16, 64);
        t[kk] = (h & 16) ? b : a;
    }
    #pragma unroll
    for (int kk = 0; kk < 2; ++kk) {
        float a = t[2 * kk]     + __shfl_xor(t[2 * kk],     8, 64);
        float b = t[2 * kk + 1] + __shfl_xor(t[2 * kk + 1], 8, 64);
        t[kk] = (h & 8) ? b : a;
    }
    {
        float a = t[0] + __shfl_xor(t[0], 4, 64);
        float b = t[1] + __shfl_xor(t[1], 4, 64);
        t[0] = (h & 4) ? b : a;
    }
    float rr = t[0];
    rr += __shfl_xor(rr, 2, 64);
    rr += __shfl_xor(rr, 1, 64);
    // lane holds logit of k = rev4(lane>>2)

    float lg = rr + ba[0];
    float mx = lg;
    mx = fmaxf(mx, __shfl_xor(mx, 4, 64));
    mx = fmaxf(mx, __shfl_xor(mx, 8, 64));
    mx = fmaxf(mx, __shfl_xor(mx, 16, 64));
    mx = fmaxf(mx, __shfl_xor(mx, 32, 64));
    float e = expf(lg - mx);
    float sm = e;
    sm += __shfl_xor(sm, 4, 64);
    sm += __shfl_xor(sm, 8, 64);
    sm += __shfl_xor(sm, 16, 64);
    sm += __shfl_xor(sm, 32, 64);
    float wk_mine = e * (1.0f / sm);

    // PV: broadcast w_k from lane rev4(k)*4 (rev4 is an involution)
    const int rev[KNB] = {0, 8, 4, 12, 2, 10, 6, 14, 1, 9, 5, 13, 3, 11, 7, 15};
    float oh = 0.f;
    #pragma unroll
    for (int k = 0; k < KNB; ++k) {
        float wk = readlane_f(wk_mine, rev[k] << 2);
        oh = fmaf(wk, v[jidx[k] * 64 + h], oh);
    }

    // Wo projection via LDS float4 broadcast reads (2 accumulator chains)
    ohs[wave][h] = oh;
    __builtin_amdgcn_wave_barrier();
    asm volatile("s_waitcnt lgkmcnt(0)" ::: "memory");
    const float4* oh4 = (const float4*)ohs[wave];
    float yy0 = bo[h], yy1 = 0.f;
    #pragma unroll
    for (int i = 0; i < 16; ++i) {
        float4 o = oh4[i];
        yy0 = fmaf(o.x, Wo[(4 * i + 0) * 64 + h], yy0);
        yy1 = fmaf(o.y, Wo[(4 * i + 1) * 64 + h], yy1);
        yy0 = fmaf(o.z, Wo[(4 * i + 2) * 64 + h], yy0);
        yy1 = fmaf(o.w, Wo[(4 * i + 3) * 64 + h], yy1);
    }
    float y = yy0 + yy1;

    // tanh-approx GELU (JAX default approximate=True)
    float t3 = y + 0.044715f * y * y * y;
    float ge = 0.5f * y * (1.0f + tanhf(0.7978845608028654f * t3));

    out[g * 64 + h] = x[g * 64 + h] + ge;
}

extern "C" void kernel_launch(void* const* d_in, const int* in_sizes, int n_in,
                              void* d_out, int out_size, void* d_ws, size_t ws_size,
                              hipStream_t stream) {
    const float* x   = (const float*)d_in[0];
    const float* pos = (const float*)d_in[1];
    const float* Wq  = (const float*)d_in[2];
    const float* bq  = (const float*)d_in[3];
    const float* Wk  = (const float*)d_in[4];
    const float* bk  = (const float*)d_in[5];
    const float* Wv  = (const float*)d_in[6];
    const float* bv  = (const float*)d_in[7];
    const float* Wpe = (const float*)d_in[8];
    const float* bpe = (const float*)d_in[9];
    const float* Wpd = (const float*)d_in[10];
    const float* bpd = (const float*)d_in[11];
    const float* Wa  = (const float*)d_in[12];
    const float* ba  = (const float*)d_in[13];
    const float* Wo  = (const float*)d_in[14];
    const float* bo  = (const float*)d_in[15];
    float* out = (float*)d_out;

    float* ws  = (float*)d_ws;
    float* qpe = ws;
    float* kpe = ws + (size_t)P_TOT * 64;
    float* vv  = ws + (size_t)2 * P_TOT * 64;
    int*   cstart = (int*)(ws + (size_t)3 * P_TOT * 64);   // 4*4097 ints
    float4* gpts = (float4*)(cstart + S_DIM * CSTRIDE);    // 16B-aligned (65552B offset)

    pre_kernel<<<PROJ_BLKS + S_DIM, 1024, 0, stream>>>(
        x, pos, Wq, bq, Wk, bk, Wv, bv, Wpe, bpe, qpe, kpe, vv, cstart, gpts);
    knn_attn_kernel<<<P_TOT / 8, 512, 0, stream>>>(
        x, pos, cstart, gpts, Wpd, bpd, Wa, ba, Wo, bo, qpe, kpe, vv, out);
}